// Round 6
// baseline (87.276 us; speedup 1.0000x reference)
//
#include <hip/hip_runtime.h>

#define NBATCH 16
#define CIN_ 128
#define COUT_ 128
#define H_ 128
#define W_ 128
#define TH 4               // output rows per workgroup
#define NR (TH + 2)        // staged input rows
#define CPITCH 34          // ci pitch in LDS tile (17-word pixel stride -> conflict-light reads)

typedef short bf16x8 __attribute__((ext_vector_type(8)));
typedef float f32x4 __attribute__((ext_vector_type(4)));

__device__ __forceinline__ unsigned short f32_to_bf16(float f) {
  unsigned int u = __float_as_uint(f);
  u += 0x7fffu + ((u >> 16) & 1u);   // round-to-nearest-even
  return (unsigned short)(u >> 16);
}

// ---------------- kernel 1: decode block mask -> active lists ----------------
__global__ void make_lists_k(const float* __restrict__ mask, int* __restrict__ lists) {
  if (threadIdx.x == 0) {
    for (int i = 0; i < 20; ++i) lists[i] = 0;
    for (int ob = 0; ob < 4; ++ob) {
      int c = 0;
      for (int ib = 0; ib < 4; ++ib) {
        float v = mask[(size_t)((ob * 32) * CIN_ + ib * 32) * 9];
        if (v != 0.0f) { lists[4 + ob * 4 + c] = ib; ++c; }
      }
      lists[ob] = c;
    }
  }
}

// ---------------- kernel 2: pack masked weights to bf16, MFMA A-layout -------
// wpack[ob][slot][khkw][co(32)][ci(32)]  (ci contiguous)
__global__ __launch_bounds__(256) void pack_w_k(const float* __restrict__ weight,
                                                const float* __restrict__ mask,
                                                const int* __restrict__ lists,
                                                unsigned short* __restrict__ wpack) {
  const int khkw = blockIdx.x;   // 0..8
  const int slot = blockIdx.y;   // 0..3
  const int ob   = blockIdx.z;   // 0..3
  if (slot >= lists[ob]) return;
  const int ib = lists[4 + ob * 4 + slot];
  const int kh = khkw / 3, kw = khkw % 3;
  for (int e = threadIdx.x; e < 1024; e += 256) {
    const int co = e >> 5, ci = e & 31;
    const int cog = ob * 32 + co, cig = ib * 32 + ci;
    const size_t widx = ((size_t)(cog * CIN_ + cig) * 3 + kh) * 3 + kw;
    const float v = weight[widx] * mask[widx];
    wpack[(size_t)((ob * 4 + slot) * 9 + khkw) * 1024 + e] = f32_to_bf16(v);
  }
}

// ---------------- kernel 3: fused transpose+conv (block-sparse implicit GEMM)
// grid: (H/TH, B, 4 output blocks), block 256 (4 waves over w), 3 WG/CU.
// Staging is hand-pipelined: 4 batches x 3 iters (6 dwordx4 each), 2-deep.
__global__ __launch_bounds__(256, 3) void conv_fused_k(const float* __restrict__ x,
                                                       const unsigned short* __restrict__ wpack,
                                                       const int* __restrict__ lists,
                                                       const float* __restrict__ bias,
                                                       float* __restrict__ out) {
  __shared__ unsigned short xs[NR * 130 * CPITCH];   // 53 KB

  const int tid  = threadIdx.x;
  const int wave = tid >> 6;
  const int lane = tid & 63;
  const int wl   = lane & 15;     // MFMA row/col index
  const int kg   = lane >> 4;     // k-group (8 consecutive k per lane)

  const int h0 = blockIdx.x * TH;
  const int b  = blockIdx.y;
  const int ob = blockIdx.z;
  const int w0 = wave * 32;

  const int cnt = lists[ob];

  f32x4 acc[TH][2][2] = {};

  // staging decomposition: quad q = w/4, group g picks (row, ci-pair)
  const int q = tid & 31;         // w quad: w = q*4 + j
  const int g = tid >> 5;         // 0..7

  for (int s = 0; s < cnt; ++s) {
    const int ib = lists[4 + ob * 4 + s];

    if (s) __syncthreads();   // previous compute done reading xs

    // ---- stage x[b][ib*32..+31][h0-1..h0+TH][*] -> xs (bf16, transposed) ----
    // Pipelined: ISSUE(b+1) before CVTW(b); >=6 loads in flight throughout.
    {
      const float* xbase = x + ((size_t)b * CIN_ + ib * 32) * H_ * W_ + q * 4;
      f32x4 va[2][3], vb[2][3];

#define ISSUE(B)                                                               \
  {                                                                            \
    _Pragma("unroll") for (int u = 0; u < 3; ++u) {                            \
      const int combo = ((B) * 3 + u) * 8 + g;                                 \
      const int r = combo >> 4;                                                \
      const int cp = combo & 15;                                               \
      const int row = h0 - 1 + r;                                              \
      const bool rv = (row >= 0) && (row < H_);                                \
      const float* src = xbase + ((size_t)(cp * 2) * H_ + (rv ? row : 0)) * W_;\
      va[(B) & 1][u] = *(const f32x4*)src;                                     \
      vb[(B) & 1][u] = *(const f32x4*)(src + (size_t)H_ * W_);                 \
    }                                                                          \
  }

#define CVTW(B)                                                                \
  {                                                                            \
    _Pragma("unroll") for (int u = 0; u < 3; ++u) {                            \
      const int combo = ((B) * 3 + u) * 8 + g;                                 \
      const int r = combo >> 4;                                                \
      const int cp = combo & 15;                                               \
      const int row = h0 - 1 + r;                                              \
      const bool rv = (row >= 0) && (row < H_);                                \
      unsigned int* xd =                                                       \
          (unsigned int*)(xs + (r * 130 + q * 4 + 1) * CPITCH + cp * 2);       \
      _Pragma("unroll") for (int j = 0; j < 4; ++j) {                          \
        unsigned int lo = rv ? (unsigned int)f32_to_bf16(va[(B) & 1][u][j]) : 0u; \
        unsigned int hi = rv ? (unsigned int)f32_to_bf16(vb[(B) & 1][u][j]) : 0u; \
        xd[j * (CPITCH / 2)] = lo | (hi << 16);                                \
      }                                                                        \
    }                                                                          \
  }

      ISSUE(0)
      ISSUE(1)
      CVTW(0)
      ISSUE(2)
      CVTW(1)
      ISSUE(3)
      CVTW(2)
      CVTW(3)
#undef ISSUE
#undef CVTW

      // zero the w' = 0 and w' = 129 padding columns (NR*2*32 = 384 elems)
      for (int e = tid; e < NR * 2 * 32; e += 256) {
        const int r = e >> 6, edge = (e >> 5) & 1, cc = e & 31;
        xs[(r * 130 + (edge ? 129 : 0)) * CPITCH + cc] = 0;
      }
    }

    // ---- hoist all 18 A fragments (L2-hot; latency hides under barrier) ----
    const unsigned short* wk =
        wpack + (size_t)((ob * 4 + s) * 9) * 1024 + wl * 32 + kg * 8;
    bf16x8 a[3][3][2];
#pragma unroll
    for (int kh = 0; kh < 3; ++kh)
#pragma unroll
      for (int kw = 0; kw < 3; ++kw) {
        a[kh][kw][0] = *(const bf16x8*)(wk + (kh * 3 + kw) * 1024);
        a[kh][kw][1] = *(const bf16x8*)(wk + (kh * 3 + kw) * 1024 + 16 * 32);
      }

    __syncthreads();   // tile staged

    // ---- compute: input-row-major, B frags from LDS ----
#pragma unroll
    for (int ridx = 0; ridx < NR; ++ridx) {
      bf16x8 bf[2][3];
#pragma unroll
      for (int ni = 0; ni < 2; ++ni)
#pragma unroll
        for (int kw = 0; kw < 3; ++kw)
          bf[ni][kw] = *(const bf16x8*)(xs + (ridx * 130 + w0 + ni * 16 + wl + kw) * CPITCH + kg * 8);

#pragma unroll
      for (int kh = 0; kh < 3; ++kh) {
        const int hi = ridx - kh;           // output row h0+hi uses input r with tap kh
        if (hi < 0 || hi >= TH) continue;   // compile-time prune
#pragma unroll
        for (int kw = 0; kw < 3; ++kw) {
          acc[hi][0][0] = __builtin_amdgcn_mfma_f32_16x16x32_bf16(a[kh][kw][0], bf[0][kw], acc[hi][0][0], 0, 0, 0);
          acc[hi][0][1] = __builtin_amdgcn_mfma_f32_16x16x32_bf16(a[kh][kw][0], bf[1][kw], acc[hi][0][1], 0, 0, 0);
          acc[hi][1][0] = __builtin_amdgcn_mfma_f32_16x16x32_bf16(a[kh][kw][1], bf[0][kw], acc[hi][1][0], 0, 0, 0);
          acc[hi][1][1] = __builtin_amdgcn_mfma_f32_16x16x32_bf16(a[kh][kw][1], bf[1][kw], acc[hi][1][1], 0, 0, 0);
        }
      }
    }
  }

  // epilogue: C/D layout col = lane&15 (w), row = (lane>>4)*4 + j (co)  [HW-verified r1]
#pragma unroll
  for (int mi = 0; mi < 2; ++mi)
#pragma unroll
    for (int j = 0; j < 4; ++j) {
      const int co = mi * 16 + kg * 4 + j;
      const float bv = bias[ob * 32 + co];
#pragma unroll
      for (int hh = 0; hh < TH; ++hh) {
        float* yrow = out + ((size_t)(b * COUT_ + ob * 32 + co) * H_ + h0 + hh) * W_;
        yrow[w0 + wl]      = acc[hh][mi][0][j] + bv;
        yrow[w0 + wl + 16] = acc[hh][mi][1][j] + bv;
      }
    }
}

extern "C" void kernel_launch(void* const* d_in, const int* in_sizes, int n_in,
                              void* d_out, int out_size, void* d_ws, size_t ws_size,
                              hipStream_t stream) {
  const float* x      = (const float*)d_in[0];
  const float* weight = (const float*)d_in[1];
  const float* bias   = (const float*)d_in[2];
  const float* mask   = (const float*)d_in[3];
  float* out = (float*)d_out;

  // ws layout: [0, 4K) : int lists ; [4K, +288K) : packed bf16 weights
  int* lists = (int*)d_ws;
  unsigned short* wpack = (unsigned short*)((char*)d_ws + 4096);

  make_lists_k<<<1, 64, 0, stream>>>(mask, lists);
  pack_w_k<<<dim3(9, 4, 4), 256, 0, stream>>>(weight, mask, lists, wpack);
  conv_fused_k<<<dim3(H_ / TH, NBATCH, 4), 256, 0, stream>>>(x, wpack, lists, bias, out);
}

// Round 7
// 79.625 us; speedup vs baseline: 1.0961x; 1.0961x over previous
//
#include <hip/hip_runtime.h>

#define NBATCH 16
#define CIN_ 128
#define COUT_ 128
#define H_ 128
#define W_ 128
#define TH 4               // output rows per workgroup
#define NR (TH + 2)        // staged input rows
#define PSTRIDE 32         // ci per pixel in LDS (bf16) -> 64 B, 16B-aligned b128 ops

typedef short bf16x8 __attribute__((ext_vector_type(8)));
typedef float f32x4 __attribute__((ext_vector_type(4)));
typedef unsigned short u16x8 __attribute__((ext_vector_type(8)));

__device__ __forceinline__ unsigned short f32_to_bf16(float f) {
  unsigned int u = __float_as_uint(f);
  u += 0x7fffu + ((u >> 16) & 1u);   // round-to-nearest-even
  return (unsigned short)(u >> 16);
}

// ---------------- kernel 1: decode block mask -> active lists ----------------
__global__ void make_lists_k(const float* __restrict__ mask, int* __restrict__ lists) {
  if (threadIdx.x == 0) {
    for (int i = 0; i < 20; ++i) lists[i] = 0;
    for (int ob = 0; ob < 4; ++ob) {
      int c = 0;
      for (int ib = 0; ib < 4; ++ib) {
        float v = mask[(size_t)((ob * 32) * CIN_ + ib * 32) * 9];
        if (v != 0.0f) { lists[4 + ob * 4 + c] = ib; ++c; }
      }
      lists[ob] = c;
    }
  }
}

// ---------------- kernel 2: pack masked weights to bf16, MFMA A-layout -------
// wpack[ob][slot][khkw][co(32)][ci(32)]  (ci contiguous)
__global__ __launch_bounds__(256) void pack_w_k(const float* __restrict__ weight,
                                                const float* __restrict__ mask,
                                                const int* __restrict__ lists,
                                                unsigned short* __restrict__ wpack) {
  const int khkw = blockIdx.x;   // 0..8
  const int slot = blockIdx.y;   // 0..3
  const int ob   = blockIdx.z;   // 0..3
  if (slot >= lists[ob]) return;
  const int ib = lists[4 + ob * 4 + slot];
  const int kh = khkw / 3, kw = khkw % 3;
  for (int e = threadIdx.x; e < 1024; e += 256) {
    const int co = e >> 5, ci = e & 31;
    const int cog = ob * 32 + co, cig = ib * 32 + ci;
    const size_t widx = ((size_t)(cog * CIN_ + cig) * 3 + kh) * 3 + kw;
    const float v = weight[widx] * mask[widx];
    wpack[(size_t)((ob * 4 + slot) * 9 + khkw) * 1024 + e] = f32_to_bf16(v);
  }
}

// ---------------- kernel 3: fused transpose+conv (block-sparse implicit GEMM)
// grid: (H/TH, B, 4 output blocks), block 256 (4 waves over w), 3 WG/CU.
// LDS tile [NR][130 pixels][32 ci] bf16, pixel stride 64 B: all LDS traffic is
// 16B-aligned b128, reads conflict-free, writes 2-way (free).
__global__ __launch_bounds__(256, 3) void conv_fused_k(const float* __restrict__ x,
                                                       const unsigned short* __restrict__ wpack,
                                                       const int* __restrict__ lists,
                                                       const float* __restrict__ bias,
                                                       float* __restrict__ out) {
  __shared__ unsigned short xs[NR * 130 * PSTRIDE];   // 49.9 KB

  const int tid  = threadIdx.x;
  const int wave = tid >> 6;
  const int lane = tid & 63;
  const int wl   = lane & 15;     // MFMA row/col index
  const int kg   = lane >> 4;     // k-group (8 consecutive k per lane)

  const int h0 = blockIdx.x * TH;
  const int b  = blockIdx.y;
  const int ob = blockIdx.z;
  const int w0 = wave * 32;

  const int cnt = lists[ob];

  f32x4 acc[TH][2][2] = {};

  // staging decomposition: q = w quad (0..31), g = (r-half, ci-oct) selector
  const int g   = tid & 7;        // oct = g&3, r-half = g>>2
  const int q   = tid >> 3;       // 0..31, w = q*4 + j
  const int oct = g & 3;          // 8-ci group

  for (int s = 0; s < cnt; ++s) {
    const int ib = lists[4 + ob * 4 + s];

    if (s) __syncthreads();   // previous compute done reading xs

    // ---- stage x[b][ib*32..+31][h0-1..h0+TH][*] -> xs (bf16, transposed) ----
    {
      const float* xbase =
          x + ((size_t)b * CIN_ + ib * 32 + oct * 8) * H_ * W_ + q * 4;
#pragma unroll
      for (int it = 0; it < 3; ++it) {
        const int r = it * 2 + (g >> 2);      // 0..5
        const int row = h0 - 1 + r;
        const bool rv = (row >= 0) && (row < H_);
        const float* src = xbase + (size_t)(rv ? row : 0) * W_;
        f32x4 v0 = *(const f32x4*)(src);
        f32x4 v1 = *(const f32x4*)(src + 1 * (size_t)H_ * W_);
        f32x4 v2 = *(const f32x4*)(src + 2 * (size_t)H_ * W_);
        f32x4 v3 = *(const f32x4*)(src + 3 * (size_t)H_ * W_);
        f32x4 v4 = *(const f32x4*)(src + 4 * (size_t)H_ * W_);
        f32x4 v5 = *(const f32x4*)(src + 5 * (size_t)H_ * W_);
        f32x4 v6 = *(const f32x4*)(src + 6 * (size_t)H_ * W_);
        f32x4 v7 = *(const f32x4*)(src + 7 * (size_t)H_ * W_);
#pragma unroll
        for (int j = 0; j < 4; ++j) {
          u16x8 o;
          if (rv) {
            o[0] = f32_to_bf16(v0[j]); o[1] = f32_to_bf16(v1[j]);
            o[2] = f32_to_bf16(v2[j]); o[3] = f32_to_bf16(v3[j]);
            o[4] = f32_to_bf16(v4[j]); o[5] = f32_to_bf16(v5[j]);
            o[6] = f32_to_bf16(v6[j]); o[7] = f32_to_bf16(v7[j]);
          } else {
            o = u16x8{0, 0, 0, 0, 0, 0, 0, 0};
          }
          // pixel = q*4 + 1 + j ; one aligned ds_write_b128
          *(u16x8*)(xs + (r * 130 + q * 4 + 1 + j) * PSTRIDE + oct * 8) = o;
        }
      }
      // zero the w' = 0 and w' = 129 padding columns (NR*2*32 = 384 halfwords)
      for (int e = tid; e < NR * 2 * 32; e += 256) {
        const int r = e >> 6, edge = (e >> 5) & 1, cc = e & 31;
        xs[(r * 130 + (edge ? 129 : 0)) * PSTRIDE + cc] = 0;
      }
    }

    // ---- hoist all 18 A fragments (L2-hot; latency hides under barrier) ----
    const unsigned short* wk =
        wpack + (size_t)((ob * 4 + s) * 9) * 1024 + wl * 32 + kg * 8;
    bf16x8 a[3][3][2];
#pragma unroll
    for (int kh = 0; kh < 3; ++kh)
#pragma unroll
      for (int kw = 0; kw < 3; ++kw) {
        a[kh][kw][0] = *(const bf16x8*)(wk + (kh * 3 + kw) * 1024);
        a[kh][kw][1] = *(const bf16x8*)(wk + (kh * 3 + kw) * 1024 + 16 * 32);
      }

    __syncthreads();   // tile staged

    // ---- compute: input-row-major, B frags from LDS (aligned b128 reads) ----
#pragma unroll
    for (int ridx = 0; ridx < NR; ++ridx) {
      bf16x8 bf[2][3];
#pragma unroll
      for (int ni = 0; ni < 2; ++ni)
#pragma unroll
        for (int kw = 0; kw < 3; ++kw)
          bf[ni][kw] = *(const bf16x8*)(xs + (ridx * 130 + w0 + ni * 16 + wl + kw) * PSTRIDE + kg * 8);

#pragma unroll
      for (int kh = 0; kh < 3; ++kh) {
        const int hi = ridx - kh;           // output row h0+hi uses input r with tap kh
        if (hi < 0 || hi >= TH) continue;   // compile-time prune
#pragma unroll
        for (int kw = 0; kw < 3; ++kw) {
          acc[hi][0][0] = __builtin_amdgcn_mfma_f32_16x16x32_bf16(a[kh][kw][0], bf[0][kw], acc[hi][0][0], 0, 0, 0);
          acc[hi][0][1] = __builtin_amdgcn_mfma_f32_16x16x32_bf16(a[kh][kw][0], bf[1][kw], acc[hi][0][1], 0, 0, 0);
          acc[hi][1][0] = __builtin_amdgcn_mfma_f32_16x16x32_bf16(a[kh][kw][1], bf[0][kw], acc[hi][1][0], 0, 0, 0);
          acc[hi][1][1] = __builtin_amdgcn_mfma_f32_16x16x32_bf16(a[kh][kw][1], bf[1][kw], acc[hi][1][1], 0, 0, 0);
        }
      }
    }
  }

  // epilogue: C/D layout col = lane&15 (w), row = (lane>>4)*4 + j (co)  [HW-verified r1]
#pragma unroll
  for (int mi = 0; mi < 2; ++mi)
#pragma unroll
    for (int j = 0; j < 4; ++j) {
      const int co = mi * 16 + kg * 4 + j;
      const float bv = bias[ob * 32 + co];
#pragma unroll
      for (int hh = 0; hh < TH; ++hh) {
        float* yrow = out + ((size_t)(b * COUT_ + ob * 32 + co) * H_ + h0 + hh) * W_;
        yrow[w0 + wl]      = acc[hh][mi][0][j] + bv;
        yrow[w0 + wl + 16] = acc[hh][mi][1][j] + bv;
      }
    }
}

extern "C" void kernel_launch(void* const* d_in, const int* in_sizes, int n_in,
                              void* d_out, int out_size, void* d_ws, size_t ws_size,
                              hipStream_t stream) {
  const float* x      = (const float*)d_in[0];
  const float* weight = (const float*)d_in[1];
  const float* bias   = (const float*)d_in[2];
  const float* mask   = (const float*)d_in[3];
  float* out = (float*)d_out;

  // ws layout: [0, 4K) : int lists ; [4K, +288K) : packed bf16 weights
  int* lists = (int*)d_ws;
  unsigned short* wpack = (unsigned short*)((char*)d_ws + 4096);

  make_lists_k<<<1, 64, 0, stream>>>(mask, lists);
  pack_w_k<<<dim3(9, 4, 4), 256, 0, stream>>>(weight, mask, lists, wpack);
  conv_fused_k<<<dim3(H_ / TH, NBATCH, 4), 256, 0, stream>>>(x, wpack, lists, bias, out);
}